// Round 14
// baseline (153.642 us; speedup 1.0000x reference)
//
#include <hip/hip_runtime.h>

// SelfAttention: y = causal_mha(x @ W_qkv^T + b_qkv)
// B=4, T=2048, C=1024, H=16, hd=64.  All I/O fp32; compute in bf16 MFMA.
//
// Pipeline:
//   1) cvt_bf16: x -> xb bf16 ; W -> Wb bf16
//   2) qkv_gemm v8 (unchanged): T3 minimum-2-phase prefetch dbuf (64KB LDS),
//      BK=64, specialized epilogue, frag-tiled outputs:
//        qS/kS: (t,d) -> ((t>>5)*4 + (d>>4))*512 + (t&31)*16 + (d&15)
//        vS:    (t,d) -> ((t>>4)*64 + d)*16 + (t&15)
//      Q pre-scaled by 0.125*log2e -> S in log2 domain.
//   3) attn v10: v9's superchunk x parity inner loop (verified), but ONE
//      superchunk per block: 2048 blocks x 2 waves = 4096 waves = 16/CU
//      (round-13 diagnosis: v9's in-block phase pairing halved occupancy to
//      8 waves/CU, grid-limited at 18%).  LPT: s = 31-idx -> longest blocks
//      first; scheduler backfills (8 blocks/CU).  Merge LDS 32->16KB via
//      sequential two-round chunk merge (A then B through one buffer) so
//      8 blocks/CU fit (128KB < 160KB).

typedef unsigned short u16;
typedef short bf16x8 __attribute__((ext_vector_type(8)));
typedef float f32x4 __attribute__((ext_vector_type(4)));
typedef float f32x16 __attribute__((ext_vector_type(16)));

__device__ __forceinline__ float exp2f_hw(float x) {
  return __builtin_amdgcn_exp2f(x);   // v_exp_f32: 2^x
}

__device__ __forceinline__ u16 f2b(float f) {
  union { float f; unsigned u; } x; x.f = f;
  unsigned r = x.u + 0x7FFFu + ((x.u >> 16) & 1u);  // RNE
  return (u16)(r >> 16);
}

__device__ __forceinline__ unsigned cvtpk(float lo, float hi_) {
  unsigned r;
  asm("v_cvt_pk_bf16_f32 %0, %1, %2" : "=v"(r) : "v"(lo), "v"(hi_));
  return r;
}

__device__ __forceinline__ void gload16(const void* g, void* l) {
  __builtin_amdgcn_global_load_lds(
      (const __attribute__((address_space(1))) unsigned*)g,
      (__attribute__((address_space(3))) unsigned*)l, 16, 0, 0);
}

// P = exp2(min(st,80)) packed into two PV A-frags (8 cvt_pk + 4 permlane)
__device__ __forceinline__ void packP(f32x16 st, bf16x8& pa0, bf16x8& pa1) {
#pragma unroll
  for (int r = 0; r < 16; ++r) st[r] = exp2f_hw(fminf(st[r], 80.f));
  {
    unsigned x0 = cvtpk(st[0], st[1]),  y0 = cvtpk(st[4], st[5]);
    unsigned x1 = cvtpk(st[2], st[3]),  y1 = cvtpk(st[6], st[7]);
    auto s0 = __builtin_amdgcn_permlane32_swap(x0, y0, false, false);
    auto s1 = __builtin_amdgcn_permlane32_swap(x1, y1, false, false);
    union { unsigned w[4]; bf16x8 v; } u;
    u.w[0] = s0[0]; u.w[1] = s1[0]; u.w[2] = s0[1]; u.w[3] = s1[1];
    pa0 = u.v;
  }
  {
    unsigned x0 = cvtpk(st[8], st[9]),   y0 = cvtpk(st[12], st[13]);
    unsigned x1 = cvtpk(st[10], st[11]), y1 = cvtpk(st[14], st[15]);
    auto s0 = __builtin_amdgcn_permlane32_swap(x0, y0, false, false);
    auto s1 = __builtin_amdgcn_permlane32_swap(x1, y1, false, false);
    union { unsigned w[4]; bf16x8 v; } u;
    u.w[0] = s0[0]; u.w[1] = s1[0]; u.w[2] = s0[1]; u.w[3] = s1[1];
    pa1 = u.v;
  }
}

// ---------------- fp32 -> bf16 convert ----------------
__global__ void cvt_bf16(const float* __restrict__ src, u16* __restrict__ dst, int n4) {
  int i = blockIdx.x * blockDim.x + threadIdx.x;
  const int stride = gridDim.x * blockDim.x;
  for (; i < n4; i += stride) {
    float4 v = ((const float4*)src)[i];
    ushort4 o;
    o.x = f2b(v.x); o.y = f2b(v.y); o.z = f2b(v.z); o.w = f2b(v.w);
    ((ushort4*)dst)[i] = o;
  }
}

// ---------------- QKV GEMM (2-phase prefetch dbuf, specialized epilogue) ----------------
__global__ __launch_bounds__(256) void qkv_gemm(
    const u16* __restrict__ Xb, const u16* __restrict__ Wb,
    const float* __restrict__ bias,
    u16* __restrict__ qw, u16* __restrict__ kw, u16* __restrict__ vw) {
  // [dbuf][As 8192 u16 | Bs 8192 u16]  (64 KB total)
  __shared__ u16 LDSbuf[2][16384];
  const int tid  = threadIdx.x;
  const int lane = tid & 63;
  const int wave = tid >> 6;
  const int ln = lane & 15, hi = lane >> 4;
  const int wr = wave >> 1, wc = wave & 1;
  const int m0 = blockIdx.y * 128;
  const int n0 = blockIdx.x * 128;
  const bool vblk = (n0 >= 2048);

  const int srow = tid >> 2;
  const int scol = (tid & 3) * 8;

  f32x4 zero = {0.f, 0.f, 0.f, 0.f};
  f32x4 acc[4][4];
#pragma unroll
  for (int i = 0; i < 4; ++i)
#pragma unroll
    for (int j = 0; j < 4; ++j) acc[i][j] = zero;

  const u16* Xb0 = Xb + (size_t)(m0 + srow) * 1024 + scol;
  const u16* Xb1 = Xb + (size_t)(m0 + 64 + srow) * 1024 + scol;
  const u16* Wb0 = Wb + (size_t)(n0 + srow) * 1024 + scol;
  const u16* Wb1 = Wb + (size_t)(n0 + 64 + srow) * 1024 + scol;

  // stage K-tile k0 into buffer cur (8 x global_load_lds width=16)
  auto STAGE = [&](int cur, int k0) {
    char* As = (char*)&LDSbuf[cur][0];
    char* Bs = (char*)&LDSbuf[cur][8192];
    gload16(Xb0 + k0,      As + tid * 16);
    gload16(Xb1 + k0,      As + 4096 + tid * 16);
    gload16(Xb0 + k0 + 32, As + 8192 + tid * 16);
    gload16(Xb1 + k0 + 32, As + 12288 + tid * 16);
    gload16(Wb0 + k0,      Bs + tid * 16);
    gload16(Wb1 + k0,      Bs + 4096 + tid * 16);
    gload16(Wb0 + k0 + 32, Bs + 8192 + tid * 16);
    gload16(Wb1 + k0 + 32, Bs + 12288 + tid * 16);
  };

  auto COMPUTE = [&](int cur) {
    const u16* As = &LDSbuf[cur][0];
    const u16* Bs = &LDSbuf[cur][8192];
#pragma unroll
    for (int hf = 0; hf < 2; ++hf) {
      const u16* Ah = As + hf * 4096;
      const u16* Bh = Bs + hf * 4096;
      bf16x8 af[4], bfv[4];
#pragma unroll
      for (int i = 0; i < 4; ++i)
        af[i] = *(const bf16x8*)&Ah[(wr * 64 + i * 16 + ln) * 32 + hi * 8];
#pragma unroll
      for (int j = 0; j < 4; ++j)
        bfv[j] = *(const bf16x8*)&Bh[(wc * 64 + j * 16 + ln) * 32 + hi * 8];
      if (vblk) {
        // C^T: D[row = W-row (d)][col = X-row (t)]
#pragma unroll
        for (int i = 0; i < 4; ++i)
#pragma unroll
          for (int j = 0; j < 4; ++j)
            acc[i][j] = __builtin_amdgcn_mfma_f32_16x16x32_bf16(bfv[j], af[i], acc[i][j], 0, 0, 0);
      } else {
#pragma unroll
        for (int i = 0; i < 4; ++i)
#pragma unroll
          for (int j = 0; j < 4; ++j)
            acc[i][j] = __builtin_amdgcn_mfma_f32_16x16x32_bf16(af[i], bfv[j], acc[i][j], 0, 0, 0);
      }
    }
  };

  // T3 minimum 2-phase: prologue stage, then {STAGE(t+1); COMPUTE(t); barrier}
  STAGE(0, 0);
  __syncthreads();            // tile 0 ready
  int cur = 0;
#pragma unroll 1
  for (int t = 0; t < 15; ++t) {
    STAGE(cur ^ 1, (t + 1) * 64);   // issue next-tile loads FIRST (fly under compute)
    COMPUTE(cur);
    __syncthreads();          // vmcnt(0)+lgkmcnt(0)+barrier: next tile ready,
    cur ^= 1;                 // this tile's reads done -> buf reusable
  }
  COMPUTE(cur);               // last tile, no prefetch

  // ---- epilogue: which/bh uniform per block(+wave) ----
  const int which = n0 >> 10;              // 0=q 1=k 2=v (uniform)
  const int h = ((n0 & 1023) >> 6) + wc;   // head (uniform per wave)
  const size_t bh = (size_t)((m0 >> 11) * 16 + h);
  const int tloc = (m0 & 2047) + wr * 64;  // wave's local t base (mult of 64)

  if (which == 2) {
    u16* ob = vw + bh * 131072;
#pragma unroll
    for (int j = 0; j < 4; ++j) {
      float bv[4];
#pragma unroll
      for (int r = 0; r < 4; ++r) bv[r] = bias[n0 + wc * 64 + j * 16 + hi * 4 + r];
#pragma unroll
      for (int i = 0; i < 4; ++i) {
        // acc[i][j][r] = V[d = j*16+hi*4+r][t = tloc+i*16+ln]
        u16* p = ob + (((tloc >> 4) + i) * 64 + j * 16 + hi * 4) * 16 + ln;
#pragma unroll
        for (int r = 0; r < 4; ++r)
          p[r * 16] = f2b(acc[i][j][r] + bv[r]);
      }
    }
  } else {
    u16* ob = (which == 0 ? qw : kw) + bh * 131072;
    const float qs = (which == 0) ? 0.1803368801111244f : 1.0f;
    const int t5 = tloc >> 5;
#pragma unroll
    for (int j = 0; j < 4; ++j) {
      const float bv = bias[n0 + wc * 64 + j * 16 + ln];
#pragma unroll
      for (int i = 0; i < 4; ++i) {
        // t = tloc+i*16+hi*4+r, d = j*16+ln
        u16* p = ob + ((t5 + (i >> 1)) * 4 + j) * 512 + ((i & 1) * 16 + hi * 4) * 16 + ln;
#pragma unroll
        for (int r = 0; r < 4; ++r)
          p[r * 16] = f2b((acc[i][j][r] + bv) * qs);
      }
    }
  }
}

// ---------------- Flash attention v10 (one superchunk/block, 2 parity waves) ----------------
__global__ __launch_bounds__(128) void attn(
    const u16* __restrict__ qw, const u16* __restrict__ kw,
    const u16* __restrict__ vw, float* __restrict__ y) {
  // single merge buffer, reused for chunk A then chunk B (16 KB)
  __shared__ float accX[2][16][64];
  __shared__ float lX[2][16][64];

  const int lane = threadIdx.x & 63;
  const int p    = threadIdx.x >> 6;   // wave index == kv parity
  const int l31 = lane & 31;
  const int hi  = lane >> 5;
  const int laneoff = l31 * 16 + hi * 8;   // element offset inside a 512-elem frag slab

  // bid = xcd + 8*(idx + 32*bhg); s = 31-idx -> longest blocks dispatch FIRST (LPT).
  const int bid = blockIdx.x;
  const int xcd = bid & 7;
  const int rest = bid >> 3;               // 0..255
  const int s   = 31 - (rest & 31);        // superchunk 0..31 (64 q-rows)
  const int bh  = xcd + 8 * (rest >> 5);   // 0..63
  const int bb  = bh >> 4, h = bh & 15;

  const u16* qb = qw + (size_t)bh * 131072;
  const u16* kb = kw + (size_t)bh * 131072;
  const u16* vb = vw + (size_t)bh * 131072;
  float* yb = y + (size_t)bb * 2048 * 1024 + (size_t)h * 64;

  bf16x8 onesf;
#pragma unroll
  for (int j = 0; j < 8; ++j) onesf[j] = (short)0x3F80;  // bf16 1.0

  const int q0 = s * 64;
  const int cA = 2 * s, cB = 2 * s + 1;    // 32-row chunks
  const int jtE = cB;                      // kv tiles 0..2s+1

  // Q (B-operand) frags for both chunks
  bf16x8 qfA[4], qfB[4];
#pragma unroll
  for (int sb = 0; sb < 4; ++sb) {
    qfA[sb] = *(const bf16x8*)&qb[(cA * 4 + sb) * 512 + laneoff];
    qfB[sb] = *(const bf16x8*)&qb[(cB * 4 + sb) * 512 + laneoff];
  }

  f32x16 accA0, accA1, acclA, accB0, accB1, acclB;
#pragma unroll
  for (int r = 0; r < 16; ++r) {
    accA0[r] = 0.f; accA1[r] = 0.f; acclA[r] = 0.f;
    accB0[r] = 0.f; accB1[r] = 0.f; acclB[r] = 0.f;
  }

  bf16x8 kf[4];
#pragma unroll
  for (int sb = 0; sb < 4; ++sb)
    kf[sb] = *(const bf16x8*)&kb[(p * 4 + sb) * 512 + laneoff];

#pragma unroll 1
  for (int jt = p; jt <= jtE; jt += 2) {
    // V (B-operand) frags: one load set feeds both chunks' PV
    bf16x8 vf[4];
    vf[0] = *(const bf16x8*)&vb[((jt * 2 + 0) * 64 +  0 + l31) * 16 + hi * 8];
    vf[1] = *(const bf16x8*)&vb[((jt * 2 + 0) * 64 + 32 + l31) * 16 + hi * 8];
    vf[2] = *(const bf16x8*)&vb[((jt * 2 + 1) * 64 +  0 + l31) * 16 + hi * 8];
    vf[3] = *(const bf16x8*)&vb[((jt * 2 + 1) * 64 + 32 + l31) * 16 + hi * 8];

    // S^T = K_tile . Q^T for both chunks
    f32x16 stA, stB;
#pragma unroll
    for (int r = 0; r < 16; ++r) { stA[r] = 0.f; stB[r] = 0.f; }
#pragma unroll
    for (int sb = 0; sb < 4; ++sb) {
      stA = __builtin_amdgcn_mfma_f32_32x32x16_bf16(kf[sb], qfA[sb], stA, 0, 0, 0);
      stB = __builtin_amdgcn_mfma_f32_32x32x16_bf16(kf[sb], qfB[sb], stB, 0, 0, 0);
    }
    // K(jt) dead: reload jt+2 (exp2+PV covers latency)
    if (jt + 2 <= jtE) {
#pragma unroll
      for (int sb = 0; sb < 4; ++sb)
        kf[sb] = *(const bf16x8*)&kb[((jt + 2) * 4 + sb) * 512 + laneoff];
    }

    // masks (wave-uniform conditions; diagonals fall on fixed parities)
    if (jt == cA) {          // p=0: cA diagonal
#pragma unroll
      for (int r = 0; r < 16; ++r) {
        const int crow = (r & 3) + 8 * (r >> 2) + 4 * hi;
        if (crow > l31) stA[r] = -1e30f;
      }
    }
    if (jt == cB) {          // p=1: cA fully masked (P=0), cB diagonal
#pragma unroll
      for (int r = 0; r < 16; ++r) {
        const int crow = (r & 3) + 8 * (r >> 2) + 4 * hi;
        stA[r] = -1e30f;
        if (crow > l31) stB[r] = -1e30f;
      }
    }

    bf16x8 pa0, pa1;
    packP(stA, pa0, pa1);
    accA0 = __builtin_amdgcn_mfma_f32_32x32x16_bf16(pa0, vf[0], accA0, 0, 0, 0);
    accA1 = __builtin_amdgcn_mfma_f32_32x32x16_bf16(pa0, vf[1], accA1, 0, 0, 0);
    acclA = __builtin_amdgcn_mfma_f32_32x32x16_bf16(pa0, onesf, acclA, 0, 0, 0);
    accA0 = __builtin_amdgcn_mfma_f32_32x32x16_bf16(pa1, vf[2], accA0, 0, 0, 0);
    accA1 = __builtin_amdgcn_mfma_f32_32x32x16_bf16(pa1, vf[3], accA1, 0, 0, 0);
    acclA = __builtin_amdgcn_mfma_f32_32x32x16_bf16(pa1, onesf, acclA, 0, 0, 0);

    packP(stB, pa0, pa1);
    accB0 = __builtin_amdgcn_mfma_f32_32x32x16_bf16(pa0, vf[0], accB0, 0, 0, 0);
    accB1 = __builtin_amdgcn_mfma_f32_32x32x16_bf16(pa0, vf[1], accB1, 0, 0, 0);
    acclB = __builtin_amdgcn_mfma_f32_32x32x16_bf16(pa0, onesf, acclB, 0, 0, 0);
    accB0 = __builtin_amdgcn_mfma_f32_32x32x16_bf16(pa1, vf[2], accB0, 0, 0, 0);
    accB1 = __builtin_amdgcn_mfma_f32_32x32x16_bf16(pa1, vf[3], accB1, 0, 0, 0);
    acclB = __builtin_amdgcn_mfma_f32_32x32x16_bf16(pa1, onesf, acclB, 0, 0, 0);
  }

  // ---- two-round pair merge via one LDS buffer (linear: no max, no exp2) ----
  // round A
  if (p == 0) {
#pragma unroll
    for (int r = 0; r < 16; ++r) { accX[0][r][lane] = accA1[r]; lX[0][r][lane] = acclA[r]; }
  } else {
#pragma unroll
    for (int r = 0; r < 16; ++r) { accX[1][r][lane] = accA0[r]; lX[1][r][lane] = acclA[r]; }
  }
  __syncthreads();   // A exports visible
#pragma unroll
  for (int r = 0; r < 16; ++r) {
    const int crow = (r & 3) + 8 * (r >> 2) + 4 * hi;
    const float own = (p == 0) ? accA0[r] : accA1[r];
    const float oth = accX[p ^ 1][r][lane];
    const float inv = 1.0f / (acclA[r] + lX[p ^ 1][r][lane]);
    yb[(size_t)(q0 + crow) * 1024 + p * 32 + l31] = (own + oth) * inv;
  }
  __syncthreads();   // A reads done -> buffer reusable
  // round B
  if (p == 0) {
#pragma unroll
    for (int r = 0; r < 16; ++r) { accX[0][r][lane] = accB1[r]; lX[0][r][lane] = acclB[r]; }
  } else {
#pragma unroll
    for (int r = 0; r < 16; ++r) { accX[1][r][lane] = accB0[r]; lX[1][r][lane] = acclB[r]; }
  }
  __syncthreads();   // B exports visible
#pragma unroll
  for (int r = 0; r < 16; ++r) {
    const int crow = (r & 3) + 8 * (r >> 2) + 4 * hi;
    const float own = (p == 0) ? accB0[r] : accB1[r];
    const float oth = accX[p ^ 1][r][lane];
    const float inv = 1.0f / (acclB[r] + lX[p ^ 1][r][lane]);
    yb[(size_t)(q0 + 32 + crow) * 1024 + p * 32 + l31] = (own + oth) * inv;
  }
}

extern "C" void kernel_launch(void* const* d_in, const int* in_sizes, int n_in,
                              void* d_out, int out_size, void* d_ws, size_t ws_size,
                              hipStream_t stream) {
  const float* x    = (const float*)d_in[0];   // [4,2048,1024]
  const float* W    = (const float*)d_in[1];   // [3072,1024]
  const float* bias = (const float*)d_in[2];   // [3072]
  float* y = (float*)d_out;

  char* ws = (char*)d_ws;
  u16* xb = (u16*)(ws);
  u16* Wb = (u16*)(ws + 16777216);
  u16* qw = (u16*)(ws + 23068672);
  u16* kw = (u16*)(ws + 39845888);
  u16* vw = (u16*)(ws + 56623104);

  cvt_bf16<<<2048, 256, 0, stream>>>(x, xb, 8388608 / 4);
  cvt_bf16<<<1024, 256, 0, stream>>>(W, Wb, 3145728 / 4);
  qkv_gemm<<<dim3(24, 64), 256, 0, stream>>>(xb, Wb, bias, qw, kw, vw);
  attn<<<2048, 128, 0, stream>>>(qw, kw, vw, y);
}

// Round 16
// 130.008 us; speedup vs baseline: 1.1818x; 1.1818x over previous
//
#include <hip/hip_runtime.h>

// SelfAttention: y = causal_mha(x @ W_qkv^T + b_qkv)
// B=4, T=2048, C=1024, H=16, hd=64.  All I/O fp32; compute in bf16 MFMA.
//
// Pipeline:
//   1) cvt_bf16: x -> xb bf16 ; W -> Wb bf16
//   2) qkv_gemm v8 (unchanged): T3 minimum-2-phase prefetch dbuf (64KB LDS),
//      BK=64, specialized epilogue, frag-tiled outputs:
//        qS/kS: (t,d) -> ((t>>5)*4 + (d>>4))*512 + (t&31)*16 + (d&15)
//        vS:    (t,d) -> ((t>>4)*64 + d)*16 + (t&15)
//      Q pre-scaled by 0.125*log2e -> S in log2 domain.
//   3) attn v9c: round-15's v9b with the ONE bug fixed: vpp init was
//      p*4096 (= per-iter stride) but V-tile jt starts at jt*2048 ->
//      p=1 waves read V(jt+1) instead of V(jt) (absmax 0.318).  Now p*2048.
//      Rest verified identical to round-13's passing addressing:
//      kpp=kb+laneoff+p*2048, prefetch kpp+4096, V offs {0,512,1024,1536}.
//      Keeps (a) strength-reduced pointers, (b) no fmin clamp.

typedef unsigned short u16;
typedef short bf16x8 __attribute__((ext_vector_type(8)));
typedef float f32x4 __attribute__((ext_vector_type(4)));
typedef float f32x16 __attribute__((ext_vector_type(16)));

__device__ __forceinline__ float exp2f_hw(float x) {
  return __builtin_amdgcn_exp2f(x);   // v_exp_f32: 2^x
}

__device__ __forceinline__ u16 f2b(float f) {
  union { float f; unsigned u; } x; x.f = f;
  unsigned r = x.u + 0x7FFFu + ((x.u >> 16) & 1u);  // RNE
  return (u16)(r >> 16);
}

__device__ __forceinline__ unsigned cvtpk(float lo, float hi_) {
  unsigned r;
  asm("v_cvt_pk_bf16_f32 %0, %1, %2" : "=v"(r) : "v"(lo), "v"(hi_));
  return r;
}

__device__ __forceinline__ void gload16(const void* g, void* l) {
  __builtin_amdgcn_global_load_lds(
      (const __attribute__((address_space(1))) unsigned*)g,
      (__attribute__((address_space(3))) unsigned*)l, 16, 0, 0);
}

// P = exp2(st) packed into two PV A-frags (8 cvt_pk + 4 permlane)
__device__ __forceinline__ void packP(f32x16 st, bf16x8& pa0, bf16x8& pa1) {
#pragma unroll
  for (int r = 0; r < 16; ++r) st[r] = exp2f_hw(st[r]);
  {
    unsigned x0 = cvtpk(st[0], st[1]),  y0 = cvtpk(st[4], st[5]);
    unsigned x1 = cvtpk(st[2], st[3]),  y1 = cvtpk(st[6], st[7]);
    auto s0 = __builtin_amdgcn_permlane32_swap(x0, y0, false, false);
    auto s1 = __builtin_amdgcn_permlane32_swap(x1, y1, false, false);
    union { unsigned w[4]; bf16x8 v; } u;
    u.w[0] = s0[0]; u.w[1] = s1[0]; u.w[2] = s0[1]; u.w[3] = s1[1];
    pa0 = u.v;
  }
  {
    unsigned x0 = cvtpk(st[8], st[9]),   y0 = cvtpk(st[12], st[13]);
    unsigned x1 = cvtpk(st[10], st[11]), y1 = cvtpk(st[14], st[15]);
    auto s0 = __builtin_amdgcn_permlane32_swap(x0, y0, false, false);
    auto s1 = __builtin_amdgcn_permlane32_swap(x1, y1, false, false);
    union { unsigned w[4]; bf16x8 v; } u;
    u.w[0] = s0[0]; u.w[1] = s1[0]; u.w[2] = s0[1]; u.w[3] = s1[1];
    pa1 = u.v;
  }
}

// ---------------- fp32 -> bf16 convert ----------------
__global__ void cvt_bf16(const float* __restrict__ src, u16* __restrict__ dst, int n4) {
  int i = blockIdx.x * blockDim.x + threadIdx.x;
  const int stride = gridDim.x * blockDim.x;
  for (; i < n4; i += stride) {
    float4 v = ((const float4*)src)[i];
    ushort4 o;
    o.x = f2b(v.x); o.y = f2b(v.y); o.z = f2b(v.z); o.w = f2b(v.w);
    ((ushort4*)dst)[i] = o;
  }
}

// ---------------- QKV GEMM (2-phase prefetch dbuf, specialized epilogue) ----------------
__global__ __launch_bounds__(256) void qkv_gemm(
    const u16* __restrict__ Xb, const u16* __restrict__ Wb,
    const float* __restrict__ bias,
    u16* __restrict__ qw, u16* __restrict__ kw, u16* __restrict__ vw) {
  // [dbuf][As 8192 u16 | Bs 8192 u16]  (64 KB total)
  __shared__ u16 LDSbuf[2][16384];
  const int tid  = threadIdx.x;
  const int lane = tid & 63;
  const int wave = tid >> 6;
  const int ln = lane & 15, hi = lane >> 4;
  const int wr = wave >> 1, wc = wave & 1;
  const int m0 = blockIdx.y * 128;
  const int n0 = blockIdx.x * 128;
  const bool vblk = (n0 >= 2048);

  const int srow = tid >> 2;
  const int scol = (tid & 3) * 8;

  f32x4 zero = {0.f, 0.f, 0.f, 0.f};
  f32x4 acc[4][4];
#pragma unroll
  for (int i = 0; i < 4; ++i)
#pragma unroll
    for (int j = 0; j < 4; ++j) acc[i][j] = zero;

  const u16* Xb0 = Xb + (size_t)(m0 + srow) * 1024 + scol;
  const u16* Xb1 = Xb + (size_t)(m0 + 64 + srow) * 1024 + scol;
  const u16* Wb0 = Wb + (size_t)(n0 + srow) * 1024 + scol;
  const u16* Wb1 = Wb + (size_t)(n0 + 64 + srow) * 1024 + scol;

  // stage K-tile k0 into buffer cur (8 x global_load_lds width=16)
  auto STAGE = [&](int cur, int k0) {
    char* As = (char*)&LDSbuf[cur][0];
    char* Bs = (char*)&LDSbuf[cur][8192];
    gload16(Xb0 + k0,      As + tid * 16);
    gload16(Xb1 + k0,      As + 4096 + tid * 16);
    gload16(Xb0 + k0 + 32, As + 8192 + tid * 16);
    gload16(Xb1 + k0 + 32, As + 12288 + tid * 16);
    gload16(Wb0 + k0,      Bs + tid * 16);
    gload16(Wb1 + k0,      Bs + 4096 + tid * 16);
    gload16(Wb0 + k0 + 32, Bs + 8192 + tid * 16);
    gload16(Wb1 + k0 + 32, Bs + 12288 + tid * 16);
  };

  auto COMPUTE = [&](int cur) {
    const u16* As = &LDSbuf[cur][0];
    const u16* Bs = &LDSbuf[cur][8192];
#pragma unroll
    for (int hf = 0; hf < 2; ++hf) {
      const u16* Ah = As + hf * 4096;
      const u16* Bh = Bs + hf * 4096;
      bf16x8 af[4], bfv[4];
#pragma unroll
      for (int i = 0; i < 4; ++i)
        af[i] = *(const bf16x8*)&Ah[(wr * 64 + i * 16 + ln) * 32 + hi * 8];
#pragma unroll
      for (int j = 0; j < 4; ++j)
        bfv[j] = *(const bf16x8*)&Bh[(wc * 64 + j * 16 + ln) * 32 + hi * 8];
      if (vblk) {
        // C^T: D[row = W-row (d)][col = X-row (t)]
#pragma unroll
        for (int i = 0; i < 4; ++i)
#pragma unroll
          for (int j = 0; j < 4; ++j)
            acc[i][j] = __builtin_amdgcn_mfma_f32_16x16x32_bf16(bfv[j], af[i], acc[i][j], 0, 0, 0);
      } else {
#pragma unroll
        for (int i = 0; i < 4; ++i)
#pragma unroll
          for (int j = 0; j < 4; ++j)
            acc[i][j] = __builtin_amdgcn_mfma_f32_16x16x32_bf16(af[i], bfv[j], acc[i][j], 0, 0, 0);
      }
    }
  };

  // T3 minimum 2-phase: prologue stage, then {STAGE(t+1); COMPUTE(t); barrier}
  STAGE(0, 0);
  __syncthreads();            // tile 0 ready
  int cur = 0;
#pragma unroll 1
  for (int t = 0; t < 15; ++t) {
    STAGE(cur ^ 1, (t + 1) * 64);   // issue next-tile loads FIRST (fly under compute)
    COMPUTE(cur);
    __syncthreads();          // vmcnt(0)+lgkmcnt(0)+barrier: next tile ready,
    cur ^= 1;                 // this tile's reads done -> buf reusable
  }
  COMPUTE(cur);               // last tile, no prefetch

  // ---- epilogue: which/bh uniform per block(+wave) ----
  const int which = n0 >> 10;              // 0=q 1=k 2=v (uniform)
  const int h = ((n0 & 1023) >> 6) + wc;   // head (uniform per wave)
  const size_t bh = (size_t)((m0 >> 11) * 16 + h);
  const int tloc = (m0 & 2047) + wr * 64;  // wave's local t base (mult of 64)

  if (which == 2) {
    u16* ob = vw + bh * 131072;
#pragma unroll
    for (int j = 0; j < 4; ++j) {
      float bv[4];
#pragma unroll
      for (int r = 0; r < 4; ++r) bv[r] = bias[n0 + wc * 64 + j * 16 + hi * 4 + r];
#pragma unroll
      for (int i = 0; i < 4; ++i) {
        // acc[i][j][r] = V[d = j*16+hi*4+r][t = tloc+i*16+ln]
        u16* p = ob + (((tloc >> 4) + i) * 64 + j * 16 + hi * 4) * 16 + ln;
#pragma unroll
        for (int r = 0; r < 4; ++r)
          p[r * 16] = f2b(acc[i][j][r] + bv[r]);
      }
    }
  } else {
    u16* ob = (which == 0 ? qw : kw) + bh * 131072;
    const float qs = (which == 0) ? 0.1803368801111244f : 1.0f;
    const int t5 = tloc >> 5;
#pragma unroll
    for (int j = 0; j < 4; ++j) {
      const float bv = bias[n0 + wc * 64 + j * 16 + ln];
#pragma unroll
      for (int i = 0; i < 4; ++i) {
        // t = tloc+i*16+hi*4+r, d = j*16+ln
        u16* p = ob + ((t5 + (i >> 1)) * 4 + j) * 512 + ((i & 1) * 16 + hi * 4) * 16 + ln;
#pragma unroll
        for (int r = 0; r < 4; ++r)
          p[r * 16] = f2b((acc[i][j][r] + bv) * qs);
      }
    }
  }
}

// ---------------- Flash attention v9c (superchunk x parity, merged) ----------------
__global__ __launch_bounds__(128) void attn(
    const u16* __restrict__ qw, const u16* __restrict__ kw,
    const u16* __restrict__ vw, float* __restrict__ y) {
  // merge buffers per chunk: [parity][r][lane] (stride-1: conflict-free)
  __shared__ float accXA[2][16][64];
  __shared__ float lXA[2][16][64];
  __shared__ float accXB[2][16][64];
  __shared__ float lXB[2][16][64];

  const int lane = threadIdx.x & 63;
  const int p    = threadIdx.x >> 6;   // wave index == kv parity
  const int l31 = lane & 31;
  const int hi  = lane >> 5;
  const int laneoff = l31 * 16 + hi * 8;   // element offset inside a 512-elem frag slab

  // bid = xcd + 8*(pr + 16*bhg): all 16 blocks of one bh on one XCD.
  const int bid = blockIdx.x;
  const int xcd = bid & 7;
  const int rest = bid >> 3;               // 0..127
  const int pr  = rest & 15;               // superchunk pair 0..15
  const int bh  = xcd + 8 * (rest >> 4);   // 0..63
  const int bb  = bh >> 4, h = bh & 15;

  const u16* qb = qw + (size_t)bh * 131072;
  const u16* kb = kw + (size_t)bh * 131072;
  const u16* vb = vw + (size_t)bh * 131072;
  float* yb = y + (size_t)bb * 2048 * 1024 + (size_t)h * 64;

  bf16x8 onesf;
#pragma unroll
  for (int j = 0; j < 8; ++j) onesf[j] = (short)0x3F80;  // bf16 1.0

#pragma unroll 1
  for (int phase = 0; phase < 2; ++phase) {
    const int s  = phase ? (15 - pr) + 16 : pr;   // superchunks {pr, 31-pr}
    const int q0 = s * 64;
    const int cA = 2 * s, cB = 2 * s + 1;    // 32-row chunks
    const int jtE = cB;                      // kv tiles 0..2s+1

    // Q (B-operand) frags for both chunks
    bf16x8 qfA[4], qfB[4];
#pragma unroll
    for (int sb = 0; sb < 4; ++sb) {
      qfA[sb] = *(const bf16x8*)&qb[(cA * 4 + sb) * 512 + laneoff];
      qfB[sb] = *(const bf16x8*)&qb[(cB * 4 + sb) * 512 + laneoff];
    }

    f32x16 accA0, accA1, acclA, accB0, accB1, acclB;
#pragma unroll
    for (int r = 0; r < 16; ++r) {
      accA0[r] = 0.f; accA1[r] = 0.f; acclA[r] = 0.f;
      accB0[r] = 0.f; accB1[r] = 0.f; acclB[r] = 0.f;
    }

    // strength-reduced running pointers (tile jt: K at jt*2048, V at jt*2048;
    // jt advances by 2 -> both advance +4096 elems/iter)
    const u16* kpp = kb + laneoff + p * 2048;          // K tile jt=p
    const u16* vpp = vb + laneoff + p * 2048;          // V tile jt=p

    bf16x8 kf[4];
#pragma unroll
    for (int sb = 0; sb < 4; ++sb)
      kf[sb] = *(const bf16x8*)(kpp + sb * 512);

#pragma unroll 1
    for (int jt = p; jt <= jtE; jt += 2) {
      // V (B-operand) frags: one load set feeds both chunks' PV
      bf16x8 vf[4];
      vf[0] = *(const bf16x8*)(vpp);
      vf[1] = *(const bf16x8*)(vpp + 512);
      vf[2] = *(const bf16x8*)(vpp + 1024);
      vf[3] = *(const bf16x8*)(vpp + 1536);

      // S^T = K_tile . Q^T for both chunks
      f32x16 stA, stB;
#pragma unroll
      for (int r = 0; r < 16; ++r) { stA[r] = 0.f; stB[r] = 0.f; }
#pragma unroll
      for (int sb = 0; sb < 4; ++sb) {
        stA = __builtin_amdgcn_mfma_f32_32x32x16_bf16(kf[sb], qfA[sb], stA, 0, 0, 0);
        stB = __builtin_amdgcn_mfma_f32_32x32x16_bf16(kf[sb], qfB[sb], stB, 0, 0, 0);
      }
      // K(jt) dead: reload jt+2 (exp2+PV covers latency)
      if (jt + 2 <= jtE) {
        const u16* kn = kpp + 4096;
#pragma unroll
        for (int sb = 0; sb < 4; ++sb)
          kf[sb] = *(const bf16x8*)(kn + sb * 512);
      }
      kpp += 4096;

      // masks (wave-uniform conditions; diagonals fall on fixed parities)
      if (jt == cA) {          // p=0: cA diagonal
#pragma unroll
        for (int r = 0; r < 16; ++r) {
          const int crow = (r & 3) + 8 * (r >> 2) + 4 * hi;
          if (crow > l31) stA[r] = -1e30f;
        }
      }
      if (jt == cB) {          // p=1: cA fully masked (P=0), cB diagonal
#pragma unroll
        for (int r = 0; r < 16; ++r) {
          const int crow = (r & 3) + 8 * (r >> 2) + 4 * hi;
          stA[r] = -1e30f;
          if (crow > l31) stB[r] = -1e30f;
        }
      }

      bf16x8 pa0, pa1;
      packP(stA, pa0, pa1);
      accA0 = __builtin_amdgcn_mfma_f32_32x32x16_bf16(pa0, vf[0], accA0, 0, 0, 0);
      accA1 = __builtin_amdgcn_mfma_f32_32x32x16_bf16(pa0, vf[1], accA1, 0, 0, 0);
      acclA = __builtin_amdgcn_mfma_f32_32x32x16_bf16(pa0, onesf, acclA, 0, 0, 0);
      accA0 = __builtin_amdgcn_mfma_f32_32x32x16_bf16(pa1, vf[2], accA0, 0, 0, 0);
      accA1 = __builtin_amdgcn_mfma_f32_32x32x16_bf16(pa1, vf[3], accA1, 0, 0, 0);
      acclA = __builtin_amdgcn_mfma_f32_32x32x16_bf16(pa1, onesf, acclA, 0, 0, 0);

      packP(stB, pa0, pa1);
      accB0 = __builtin_amdgcn_mfma_f32_32x32x16_bf16(pa0, vf[0], accB0, 0, 0, 0);
      accB1 = __builtin_amdgcn_mfma_f32_32x32x16_bf16(pa0, vf[1], accB1, 0, 0, 0);
      acclB = __builtin_amdgcn_mfma_f32_32x32x16_bf16(pa0, onesf, acclB, 0, 0, 0);
      accB0 = __builtin_amdgcn_mfma_f32_32x32x16_bf16(pa1, vf[2], accB0, 0, 0, 0);
      accB1 = __builtin_amdgcn_mfma_f32_32x32x16_bf16(pa1, vf[3], accB1, 0, 0, 0);
      acclB = __builtin_amdgcn_mfma_f32_32x32x16_bf16(pa1, onesf, acclB, 0, 0, 0);

      vpp += 4096;
    }

    // ---- pair merge via LDS (linear: no max, no exp2) ----
    __syncthreads();   // protect previous phase's LDS reads
    if (p == 0) {
#pragma unroll
      for (int r = 0; r < 16; ++r) {
        accXA[0][r][lane] = accA1[r]; lXA[0][r][lane] = acclA[r];
        accXB[0][r][lane] = accB1[r]; lXB[0][r][lane] = acclB[r];
      }
    } else {
#pragma unroll
      for (int r = 0; r < 16; ++r) {
        accXA[1][r][lane] = accA0[r]; lXA[1][r][lane] = acclA[r];
        accXB[1][r][lane] = accB0[r]; lXB[1][r][lane] = acclB[r];
      }
    }
    __syncthreads();   // exports visible

    // p==0 merges d 0..31; p==1 merges d 32..63 (round-10 pattern, x2 chunks)
#pragma unroll
    for (int r = 0; r < 16; ++r) {
      const int crow = (r & 3) + 8 * (r >> 2) + 4 * hi;
      const float ownA = (p == 0) ? accA0[r] : accA1[r];
      const float othA = accXA[p ^ 1][r][lane];
      const float invA = 1.0f / (acclA[r] + lXA[p ^ 1][r][lane]);
      yb[(size_t)(q0 + crow) * 1024 + p * 32 + l31] = (ownA + othA) * invA;

      const float ownB = (p == 0) ? accB0[r] : accB1[r];
      const float othB = accXB[p ^ 1][r][lane];
      const float invB = 1.0f / (acclB[r] + lXB[p ^ 1][r][lane]);
      yb[(size_t)(q0 + 32 + crow) * 1024 + p * 32 + l31] = (ownB + othB) * invB;
    }
  }
}

extern "C" void kernel_launch(void* const* d_in, const int* in_sizes, int n_in,
                              void* d_out, int out_size, void* d_ws, size_t ws_size,
                              hipStream_t stream) {
  const float* x    = (const float*)d_in[0];   // [4,2048,1024]
  const float* W    = (const float*)d_in[1];   // [3072,1024]
  const float* bias = (const float*)d_in[2];   // [3072]
  float* y = (float*)d_out;

  char* ws = (char*)d_ws;
  u16* xb = (u16*)(ws);
  u16* Wb = (u16*)(ws + 16777216);
  u16* qw = (u16*)(ws + 23068672);
  u16* kw = (u16*)(ws + 39845888);
  u16* vw = (u16*)(ws + 56623104);

  cvt_bf16<<<2048, 256, 0, stream>>>(x, xb, 8388608 / 4);
  cvt_bf16<<<1024, 256, 0, stream>>>(W, Wb, 3145728 / 4);
  qkv_gemm<<<dim3(24, 64), 256, 0, stream>>>(xb, Wb, bias, qw, kw, vw);
  attn<<<1024, 128, 0, stream>>>(qw, kw, vw, y);
}